// Round 1
// baseline (71.674 us; speedup 1.0000x reference)
//
#include <hip/hip_runtime.h>

#define NCLS 10
#define IGN 10
#define HW_ (512 * 512)          // 262144 = 2^18
#define BATCH 8
#define NPIX (BATCH * HW_)       // 2097152
#define THREADS 256
#define PIXPERTHREAD 4
#define NBLOCKS (NPIX / (THREADS * PIXPERTHREAD))  // 2048
#define STAT_STRIDE 16           // pad each stat to its own 64B line
#define LAMBDA_UNC 0.5f

__global__ void awce_zero_stats(float* __restrict__ stats) {
    int i = threadIdx.x;
    if (i < 30 * STAT_STRIDE) stats[i] = 0.0f;
}

__global__ __launch_bounds__(THREADS) void awce_main(
    const float* __restrict__ logits,
    const int* __restrict__ targets,
    float* __restrict__ stats)
{
    const int gtid = blockIdx.x * THREADS + threadIdx.x;
    const int p0 = gtid * PIXPERTHREAD;
    const int b = p0 >> 18;               // / HW_
    const int hw = p0 & (HW_ - 1);        // % HW_
    const float* base = logits + (size_t)b * (NCLS * (size_t)HW_) + hw;

    // Load 10 channels x 4 pixels, fully unrolled -> registers only.
    float x[NCLS][4];
#pragma unroll
    for (int c = 0; c < NCLS; ++c) {
        float4 v = *reinterpret_cast<const float4*>(base + (size_t)c * HW_);
        x[c][0] = v.x; x[c][1] = v.y; x[c][2] = v.z; x[c][3] = v.w;
    }
    int4 t4 = *reinterpret_cast<const int4*>(targets + p0);
    int t[4] = {t4.x, t4.y, t4.z, t4.w};

    float cnt[NCLS], es[NCLS], cs[NCLS];
#pragma unroll
    for (int c = 0; c < NCLS; ++c) { cnt[c] = 0.f; es[c] = 0.f; cs[c] = 0.f; }

#pragma unroll
    for (int j = 0; j < PIXPERTHREAD; ++j) {
        const int tj = t[j];
        const bool valid = (tj != IGN);
        const int tc = valid ? tj : (NCLS - 1);   // clip(t,0,9)

        float m = x[0][j];
#pragma unroll
        for (int c = 1; c < NCLS; ++c) m = fmaxf(m, x[c][j]);

        float s = 0.f, dot = 0.f, xt = 0.f;
#pragma unroll
        for (int c = 0; c < NCLS; ++c) {
            const float xc = x[c][j];
            const float e = __expf(xc - m);
            s += e;
            dot = fmaf(e, xc, dot);
            xt = (tc == c) ? xc : xt;             // compile-time-indexed select
        }
        const float lse = m + __logf(s);
        const float ent = lse - dot / s;          // == -sum p*log p
        const float ce = lse - xt;

#pragma unroll
        for (int c = 0; c < NCLS; ++c) {
            const float match = (valid && (tc == c)) ? 1.f : 0.f;
            cnt[c] += match;
            es[c] = fmaf(match, ent, es[c]);
            cs[c] = fmaf(match, ce, cs[c]);
        }
    }

    // Wave64 butterfly reduce of the 30 per-class stats.
#pragma unroll
    for (int c = 0; c < NCLS; ++c) {
#pragma unroll
        for (int o = 32; o >= 1; o >>= 1) {
            cnt[c] += __shfl_xor(cnt[c], o);
            es[c]  += __shfl_xor(es[c],  o);
            cs[c]  += __shfl_xor(cs[c],  o);
        }
    }

    __shared__ float red[THREADS / 64][30];
    const int wave = threadIdx.x >> 6;
    const int lane = threadIdx.x & 63;
    if (lane == 0) {
#pragma unroll
        for (int c = 0; c < NCLS; ++c) {
            red[wave][c]      = cnt[c];
            red[wave][10 + c] = es[c];
            red[wave][20 + c] = cs[c];
        }
    }
    __syncthreads();
    const int sidx = threadIdx.x;
    if (sidx < 30) {
        float v = red[0][sidx] + red[1][sidx] + red[2][sidx] + red[3][sidx];
        atomicAdd(&stats[sidx * STAT_STRIDE], v);
    }
}

__global__ void awce_final(const float* __restrict__ stats, float* __restrict__ out) {
    if (threadIdx.x == 0) {
        float cnt[NCLS], es[NCLS], cs[NCLS];
        float nv = 0.f;
#pragma unroll
        for (int c = 0; c < NCLS; ++c) {
            cnt[c] = stats[c * STAT_STRIDE];
            es[c]  = stats[(10 + c) * STAT_STRIDE];
            cs[c]  = stats[(20 + c) * STAT_STRIDE];
            nv += cnt[c];
        }
        float loss = 0.f;
#pragma unroll
        for (int c = 0; c < NCLS; ++c) {
            float wb = 0.f;
            if (cnt[c] > 0.f && nv > 0.f) wb = (nv - cnt[c]) / fmaxf(nv, 1.f);
            const float em = (cnt[c] > 0.f) ? es[c] / fmaxf(cnt[c], 1.f) : 0.f;
            const float wc = wb * (1.f + LAMBDA_UNC * em);
            loss = fmaf(cs[c], wc, loss);
        }
        out[0] = loss / (nv + 1e-6f);
    }
}

extern "C" void kernel_launch(void* const* d_in, const int* in_sizes, int n_in,
                              void* d_out, int out_size, void* d_ws, size_t ws_size,
                              hipStream_t stream) {
    const float* logits = (const float*)d_in[0];
    const int* targets = (const int*)d_in[1];
    float* stats = (float*)d_ws;      // 30 * STAT_STRIDE floats = 1920 B
    float* out = (float*)d_out;

    awce_zero_stats<<<1, 512, 0, stream>>>(stats);
    awce_main<<<NBLOCKS, THREADS, 0, stream>>>(logits, targets, stats);
    awce_final<<<1, 64, 0, stream>>>(stats, out);
}

// Round 2
// 32.558 us; speedup vs baseline: 2.2015x; 2.2015x over previous
//
#include <hip/hip_runtime.h>

#define NCLS 10
#define IGN 10
#define HW_ (512 * 512)          // 262144 = 2^18
#define BATCH 8
#define NPIX (BATCH * HW_)       // 2097152
#define THREADS 256
#define PIXPERTHREAD 4
#define NBLOCKS (NPIX / (THREADS * PIXPERTHREAD))  // 2048
#define STAT_STRIDE 16
#define LAMBDA_UNC 0.5f

// ---------------- fallback (atomic) path helpers ----------------
__global__ void awce_zero_stats(float* __restrict__ stats) {
    int i = threadIdx.x;
    if (i < 30 * STAT_STRIDE) stats[i] = 0.0f;
}

// Main kernel. ATOMIC=false: store 30 per-block partials to partials[c*NBLOCKS+blk].
// ATOMIC=true: atomicAdd into stats[c*STAT_STRIDE] (round-1 behavior, ws-size fallback).
template <bool ATOMIC>
__global__ __launch_bounds__(THREADS) void awce_main(
    const float* __restrict__ logits,
    const int* __restrict__ targets,
    float* __restrict__ outbuf)
{
    const int gtid = blockIdx.x * THREADS + threadIdx.x;
    const int p0 = gtid * PIXPERTHREAD;
    const int b = p0 >> 18;               // / HW_
    const int hw = p0 & (HW_ - 1);        // % HW_
    const float* base = logits + (size_t)b * (NCLS * (size_t)HW_) + hw;

    float x[NCLS][4];
#pragma unroll
    for (int c = 0; c < NCLS; ++c) {
        float4 v = *reinterpret_cast<const float4*>(base + (size_t)c * HW_);
        x[c][0] = v.x; x[c][1] = v.y; x[c][2] = v.z; x[c][3] = v.w;
    }
    int4 t4 = *reinterpret_cast<const int4*>(targets + p0);
    int t[4] = {t4.x, t4.y, t4.z, t4.w};

    float cnt[NCLS], es[NCLS], cs[NCLS];
#pragma unroll
    for (int c = 0; c < NCLS; ++c) { cnt[c] = 0.f; es[c] = 0.f; cs[c] = 0.f; }

#pragma unroll
    for (int j = 0; j < PIXPERTHREAD; ++j) {
        const int tj = t[j];
        const bool valid = (tj != IGN);
        const int tc = valid ? tj : (NCLS - 1);

        float m = x[0][j];
#pragma unroll
        for (int c = 1; c < NCLS; ++c) m = fmaxf(m, x[c][j]);

        float s = 0.f, dot = 0.f, xt = 0.f;
#pragma unroll
        for (int c = 0; c < NCLS; ++c) {
            const float xc = x[c][j];
            const float e = __expf(xc - m);
            s += e;
            dot = fmaf(e, xc, dot);
            xt = (tc == c) ? xc : xt;
        }
        const float lse = m + __logf(s);
        const float ent = lse - dot / s;
        const float ce = lse - xt;

#pragma unroll
        for (int c = 0; c < NCLS; ++c) {
            const float match = (valid && (tc == c)) ? 1.f : 0.f;
            cnt[c] += match;
            es[c] = fmaf(match, ent, es[c]);
            cs[c] = fmaf(match, ce, cs[c]);
        }
    }

    // Wave64 butterfly reduce of the 30 per-class stats.
#pragma unroll
    for (int c = 0; c < NCLS; ++c) {
#pragma unroll
        for (int o = 32; o >= 1; o >>= 1) {
            cnt[c] += __shfl_xor(cnt[c], o);
            es[c]  += __shfl_xor(es[c],  o);
            cs[c]  += __shfl_xor(cs[c],  o);
        }
    }

    __shared__ float red[THREADS / 64][30];
    const int wave = threadIdx.x >> 6;
    const int lane = threadIdx.x & 63;
    if (lane == 0) {
#pragma unroll
        for (int c = 0; c < NCLS; ++c) {
            red[wave][c]      = cnt[c];
            red[wave][10 + c] = es[c];
            red[wave][20 + c] = cs[c];
        }
    }
    __syncthreads();
    const int sidx = threadIdx.x;
    if (sidx < 30) {
        float v = red[0][sidx] + red[1][sidx] + red[2][sidx] + red[3][sidx];
        if (ATOMIC) {
            atomicAdd(&outbuf[sidx * STAT_STRIDE], v);
        } else {
            outbuf[sidx * NBLOCKS + blockIdx.x] = v;   // plain store, no contention
        }
    }
}

// Reduce 30 x NBLOCKS partials, compute final loss. One block, 512 threads (8 waves).
__global__ __launch_bounds__(512) void awce_final_partials(
    const float* __restrict__ partials, float* __restrict__ out)
{
    __shared__ float sred[32];
    const int wave = threadIdx.x >> 6;
    const int lane = threadIdx.x & 63;
#pragma unroll
    for (int k = 0; k < 4; ++k) {
        const int c = wave + k * 8;       // 0..31; 30/31 unused
        if (c < 30) {
            const float* col = partials + (size_t)c * NBLOCKS;
            float s = 0.f;
#pragma unroll
            for (int i = 0; i < NBLOCKS / 64; ++i) s += col[lane + 64 * i];
#pragma unroll
            for (int o = 32; o >= 1; o >>= 1) s += __shfl_xor(s, o);
            if (lane == 0) sred[c] = s;
        }
    }
    __syncthreads();
    if (threadIdx.x == 0) {
        float cnt[NCLS], es[NCLS], cs[NCLS];
        float nv = 0.f;
#pragma unroll
        for (int c = 0; c < NCLS; ++c) {
            cnt[c] = sred[c];
            es[c]  = sred[10 + c];
            cs[c]  = sred[20 + c];
            nv += cnt[c];
        }
        float loss = 0.f;
#pragma unroll
        for (int c = 0; c < NCLS; ++c) {
            float wb = 0.f;
            if (cnt[c] > 0.f && nv > 0.f) wb = (nv - cnt[c]) / fmaxf(nv, 1.f);
            const float em = (cnt[c] > 0.f) ? es[c] / fmaxf(cnt[c], 1.f) : 0.f;
            const float wc = wb * (1.f + LAMBDA_UNC * em);
            loss = fmaf(cs[c], wc, loss);
        }
        out[0] = loss / (nv + 1e-6f);
    }
}

// Fallback finalizer reading the strided atomic stats buffer.
__global__ void awce_final_atomic(const float* __restrict__ stats, float* __restrict__ out) {
    if (threadIdx.x == 0) {
        float cnt[NCLS], es[NCLS], cs[NCLS];
        float nv = 0.f;
#pragma unroll
        for (int c = 0; c < NCLS; ++c) {
            cnt[c] = stats[c * STAT_STRIDE];
            es[c]  = stats[(10 + c) * STAT_STRIDE];
            cs[c]  = stats[(20 + c) * STAT_STRIDE];
            nv += cnt[c];
        }
        float loss = 0.f;
#pragma unroll
        for (int c = 0; c < NCLS; ++c) {
            float wb = 0.f;
            if (cnt[c] > 0.f && nv > 0.f) wb = (nv - cnt[c]) / fmaxf(nv, 1.f);
            const float em = (cnt[c] > 0.f) ? es[c] / fmaxf(cnt[c], 1.f) : 0.f;
            const float wc = wb * (1.f + LAMBDA_UNC * em);
            loss = fmaf(cs[c], wc, loss);
        }
        out[0] = loss / (nv + 1e-6f);
    }
}

extern "C" void kernel_launch(void* const* d_in, const int* in_sizes, int n_in,
                              void* d_out, int out_size, void* d_ws, size_t ws_size,
                              hipStream_t stream) {
    const float* logits = (const float*)d_in[0];
    const int* targets = (const int*)d_in[1];
    float* out = (float*)d_out;
    float* ws = (float*)d_ws;

    const size_t need = (size_t)30 * NBLOCKS * sizeof(float);   // 245,760 B
    if (ws_size >= need) {
        awce_main<false><<<NBLOCKS, THREADS, 0, stream>>>(logits, targets, ws);
        awce_final_partials<<<1, 512, 0, stream>>>(ws, out);
    } else {
        awce_zero_stats<<<1, 512, 0, stream>>>(ws);
        awce_main<true><<<NBLOCKS, THREADS, 0, stream>>>(logits, targets, ws);
        awce_final_atomic<<<1, 64, 0, stream>>>(ws, out);
    }
}

// Round 3
// 27.714 us; speedup vs baseline: 2.5862x; 1.1748x over previous
//
#include <hip/hip_runtime.h>

#define NCLS 10
#define IGN 10
#define HW_ (512 * 512)          // 262144 = 2^18
#define BATCH 8
#define NPIX (BATCH * HW_)       // 2097152
#define THREADS 256
#define PIXPERTHREAD 4
#define CHUNKS 4
#define NBLOCKS (NPIX / (THREADS * PIXPERTHREAD * CHUNKS))  // 512
#define STAT_STRIDE 16
#define LAMBDA_UNC 0.5f

// ---------------- fallback (atomic) path ----------------
__global__ void awce_zero_stats(float* __restrict__ stats) {
    int i = threadIdx.x;
    if (i < 30 * STAT_STRIDE) stats[i] = 0.0f;
}

template <bool ATOMIC>
__global__ __launch_bounds__(THREADS) void awce_main(
    const float* __restrict__ logits,
    const int* __restrict__ targets,
    float* __restrict__ outbuf)
{
    const int tid = threadIdx.x;

    float cnt[NCLS], es[NCLS], cs[NCLS];
#pragma unroll
    for (int c = 0; c < NCLS; ++c) { cnt[c] = 0.f; es[c] = 0.f; cs[c] = 0.f; }

    // Double-buffered registers: 2 x (10 channels x 4 pixels) + targets.
    float xb_[2][NCLS][4];
    int tb_[2][4];

    // chunk k pixel base
    auto chunk_p0 = [&](int k) {
        return ((blockIdx.x * CHUNKS + k) * THREADS + tid) * PIXPERTHREAD;
    };

    // load chunk k into buffer slot (compile-time slot via unrolled callers)
#define LOAD_CHUNK(k, slot)                                                        \
    {                                                                              \
        const int p0 = chunk_p0(k);                                                \
        const int b = p0 >> 18;                                                    \
        const int hw = p0 & (HW_ - 1);                                             \
        const float* base = logits + (size_t)b * (NCLS * (size_t)HW_) + hw;        \
        _Pragma("unroll")                                                          \
        for (int c = 0; c < NCLS; ++c) {                                           \
            float4 v = *reinterpret_cast<const float4*>(base + (size_t)c * HW_);   \
            xb_[slot][c][0] = v.x; xb_[slot][c][1] = v.y;                          \
            xb_[slot][c][2] = v.z; xb_[slot][c][3] = v.w;                          \
        }                                                                          \
        int4 t4 = *reinterpret_cast<const int4*>(targets + p0);                    \
        tb_[slot][0] = t4.x; tb_[slot][1] = t4.y;                                  \
        tb_[slot][2] = t4.z; tb_[slot][3] = t4.w;                                  \
    }

#define PROC_CHUNK(slot)                                                           \
    {                                                                              \
        _Pragma("unroll")                                                          \
        for (int j = 0; j < PIXPERTHREAD; ++j) {                                   \
            const int tj = tb_[slot][j];                                           \
            const bool valid = (tj != IGN);                                        \
            const int tc = valid ? tj : (NCLS - 1);                                \
            float m = xb_[slot][0][j];                                             \
            _Pragma("unroll")                                                      \
            for (int c = 1; c < NCLS; ++c) m = fmaxf(m, xb_[slot][c][j]);          \
            float s = 0.f, dot = 0.f, xt = 0.f;                                    \
            _Pragma("unroll")                                                      \
            for (int c = 0; c < NCLS; ++c) {                                       \
                const float xc = xb_[slot][c][j];                                  \
                const float e = __expf(xc - m);                                    \
                s += e;                                                            \
                dot = fmaf(e, xc, dot);                                            \
                xt = (tc == c) ? xc : xt;                                          \
            }                                                                      \
            const float lse = m + __logf(s);                                       \
            const float ent = lse - dot / s;                                       \
            const float ce = lse - xt;                                             \
            _Pragma("unroll")                                                      \
            for (int c = 0; c < NCLS; ++c) {                                       \
                const float match = (valid && (tc == c)) ? 1.f : 0.f;              \
                cnt[c] += match;                                                   \
                es[c] = fmaf(match, ent, es[c]);                                   \
                cs[c] = fmaf(match, ce, cs[c]);                                    \
            }                                                                      \
        }                                                                          \
    }

    LOAD_CHUNK(0, 0)
#pragma unroll
    for (int k = 0; k < CHUNKS; ++k) {
        if (k + 1 < CHUNKS) {
            if ((k + 1) & 1) LOAD_CHUNK(k + 1, 1) else LOAD_CHUNK(k + 1, 0)
        }
        if (k & 1) PROC_CHUNK(1) else PROC_CHUNK(0)
    }

    // Wave64 butterfly reduce of the 30 per-class stats (once per thread).
#pragma unroll
    for (int c = 0; c < NCLS; ++c) {
#pragma unroll
        for (int o = 32; o >= 1; o >>= 1) {
            cnt[c] += __shfl_xor(cnt[c], o);
            es[c]  += __shfl_xor(es[c],  o);
            cs[c]  += __shfl_xor(cs[c],  o);
        }
    }

    __shared__ float red[THREADS / 64][30];
    const int wave = tid >> 6;
    const int lane = tid & 63;
    if (lane == 0) {
#pragma unroll
        for (int c = 0; c < NCLS; ++c) {
            red[wave][c]      = cnt[c];
            red[wave][10 + c] = es[c];
            red[wave][20 + c] = cs[c];
        }
    }
    __syncthreads();
    if (tid < 30) {
        float v = red[0][tid] + red[1][tid] + red[2][tid] + red[3][tid];
        if (ATOMIC) {
            atomicAdd(&outbuf[tid * STAT_STRIDE], v);
        } else {
            outbuf[tid * NBLOCKS + blockIdx.x] = v;
        }
    }
#undef LOAD_CHUNK
#undef PROC_CHUNK
}

// Reduce 30 x NBLOCKS partials, compute final loss. One block, 512 threads.
__global__ __launch_bounds__(512) void awce_final_partials(
    const float* __restrict__ partials, float* __restrict__ out)
{
    __shared__ float sred[32];
    const int wave = threadIdx.x >> 6;
    const int lane = threadIdx.x & 63;
#pragma unroll
    for (int k = 0; k < 4; ++k) {
        const int c = wave + k * 8;
        if (c < 30) {
            const float* col = partials + (size_t)c * NBLOCKS;
            float s = 0.f;
#pragma unroll
            for (int i = 0; i < NBLOCKS / 64; ++i) s += col[lane + 64 * i];
#pragma unroll
            for (int o = 32; o >= 1; o >>= 1) s += __shfl_xor(s, o);
            if (lane == 0) sred[c] = s;
        }
    }
    __syncthreads();
    if (threadIdx.x == 0) {
        float cnt[NCLS], es[NCLS], cs[NCLS];
        float nv = 0.f;
#pragma unroll
        for (int c = 0; c < NCLS; ++c) {
            cnt[c] = sred[c];
            es[c]  = sred[10 + c];
            cs[c]  = sred[20 + c];
            nv += cnt[c];
        }
        float loss = 0.f;
#pragma unroll
        for (int c = 0; c < NCLS; ++c) {
            float wb = 0.f;
            if (cnt[c] > 0.f && nv > 0.f) wb = (nv - cnt[c]) / fmaxf(nv, 1.f);
            const float em = (cnt[c] > 0.f) ? es[c] / fmaxf(cnt[c], 1.f) : 0.f;
            const float wc = wb * (1.f + LAMBDA_UNC * em);
            loss = fmaf(cs[c], wc, loss);
        }
        out[0] = loss / (nv + 1e-6f);
    }
}

__global__ void awce_final_atomic(const float* __restrict__ stats, float* __restrict__ out) {
    if (threadIdx.x == 0) {
        float cnt[NCLS], es[NCLS], cs[NCLS];
        float nv = 0.f;
#pragma unroll
        for (int c = 0; c < NCLS; ++c) {
            cnt[c] = stats[c * STAT_STRIDE];
            es[c]  = stats[(10 + c) * STAT_STRIDE];
            cs[c]  = stats[(20 + c) * STAT_STRIDE];
            nv += cnt[c];
        }
        float loss = 0.f;
#pragma unroll
        for (int c = 0; c < NCLS; ++c) {
            float wb = 0.f;
            if (cnt[c] > 0.f && nv > 0.f) wb = (nv - cnt[c]) / fmaxf(nv, 1.f);
            const float em = (cnt[c] > 0.f) ? es[c] / fmaxf(cnt[c], 1.f) : 0.f;
            const float wc = wb * (1.f + LAMBDA_UNC * em);
            loss = fmaf(cs[c], wc, loss);
        }
        out[0] = loss / (nv + 1e-6f);
    }
}

extern "C" void kernel_launch(void* const* d_in, const int* in_sizes, int n_in,
                              void* d_out, int out_size, void* d_ws, size_t ws_size,
                              hipStream_t stream) {
    const float* logits = (const float*)d_in[0];
    const int* targets = (const int*)d_in[1];
    float* out = (float*)d_out;
    float* ws = (float*)d_ws;

    const size_t need = (size_t)30 * NBLOCKS * sizeof(float);   // 61,440 B
    if (ws_size >= need) {
        awce_main<false><<<NBLOCKS, THREADS, 0, stream>>>(logits, targets, ws);
        awce_final_partials<<<1, 512, 0, stream>>>(ws, out);
    } else {
        awce_zero_stats<<<1, 512, 0, stream>>>(ws);
        awce_main<true><<<NBLOCKS, THREADS, 0, stream>>>(logits, targets, ws);
        awce_final_atomic<<<1, 64, 0, stream>>>(ws, out);
    }
}